// Round 10
// baseline (929.333 us; speedup 1.0000x reference)
//
#include <hip/hip_runtime.h>

#define N_IND 100000
#define N_COM 100000
#define N_TRU 100000
#define NTOT  300000
#define NEDGE 4800000
#define HDIM  64
#define CHUNK 8192
#define NCHUNKS 586   // ceil(NEDGE/CHUNK)
#define NCB 293       // ceil(NTOT/1024) coarse buckets of 1024 nodes
#define PADW 33       // 32 cols + 1 pad: copy-in/out <=2-way bank alias (free)

typedef float v4f __attribute__((ext_vector_type(4)));
typedef unsigned short v4u __attribute__((ext_vector_type(4)));  // clang vector: ok for nontemporal builtins

static __device__ __forceinline__ float elem4(const float4 v, int j) {
  return j == 0 ? v.x : j == 1 ? v.y : j == 2 ? v.z : v.w;
}

// fp32 -> bf16 round-to-nearest-even
static __device__ __forceinline__ unsigned short f2bf(float f) {
  unsigned u = __float_as_uint(f);
  unsigned r = (u + 0x7FFFu + ((u >> 16) & 1u)) >> 16;
  return (unsigned short)r;
}
static __device__ __forceinline__ float bf2f(unsigned short h) {
  return __uint_as_float(((unsigned)h) << 16);
}

// Coalesced fp32 epilogue via LDS (full 64B lines per store instruction).
static __device__ __forceinline__ void store_rows_f32(
    float* __restrict__ out, float* __restrict__ st, const float* acc,
    int node0, int rows, int tid, bool active) {
#pragma unroll
  for (int stage = 0; stage < 2; ++stage) {
    __syncthreads();
    if (active) {
#pragma unroll
      for (int j = 0; j < 32; ++j) st[tid * PADW + j] = acc[stage * 32 + j];
    }
    __syncthreads();
#pragma unroll
    for (int it = 0; it < 8; ++it) {
      int e = it * 256 + tid;
      int r = e >> 3;
      int c = (e & 7) * 4;
      if (r < rows) {
        float4 o;
        o.x = st[r * PADW + c + 0];
        o.y = st[r * PADW + c + 1];
        o.z = st[r * PADW + c + 2];
        o.w = st[r * PADW + c + 3];
        *(float4*)(out + (size_t)(node0 + r) * HDIM + stage * 32 + c) = o;
      }
    }
  }
}

// Coalesced bf16 epilogue: line-complete ushort4 runs.
static __device__ __forceinline__ void store_rows_bf16(
    unsigned short* __restrict__ out, float* __restrict__ st, const float* acc,
    int node0, int rows, int tid, bool active) {
#pragma unroll
  for (int stage = 0; stage < 2; ++stage) {
    __syncthreads();
    if (active) {
#pragma unroll
      for (int j = 0; j < 32; ++j) st[tid * PADW + j] = acc[stage * 32 + j];
    }
    __syncthreads();
#pragma unroll
    for (int it = 0; it < 8; ++it) {
      int e = it * 256 + tid;
      int r = e >> 3;
      int c = (e & 7) * 4;
      if (r < rows) {
        v4u o;
        o.x = f2bf(st[r * PADW + c + 0]);
        o.y = f2bf(st[r * PADW + c + 1]);
        o.z = f2bf(st[r * PADW + c + 2]);
        o.w = f2bf(st[r * PADW + c + 3]);
        *(v4u*)(out + (size_t)(node0 + r) * HDIM + stage * 32 + c) = o;
      }
    }
  }
}

// ---------------- encoder: xb[base+n] = bf16(x[n] @ W + b) ----------------
template <int K>
__global__ __launch_bounds__(256, 2) void encode_kernel(
    const float* __restrict__ xin, const float* __restrict__ W,
    const float* __restrict__ b, unsigned short* __restrict__ xbout, int n, int base) {
  __shared__ float st[256 * PADW];
  int tid = threadIdx.x;
  int node0 = blockIdx.x * 256;
  int node = node0 + tid;
  bool active = node < n;
  int rows = min(256, n - node0);
  float acc[HDIM];
  if (active) {
    float4 row[K / 4];
    const float4* xv = (const float4*)(xin + (size_t)node * K);
#pragma unroll
    for (int i = 0; i < K / 4; ++i) row[i] = xv[i];
#pragma unroll
    for (int f = 0; f < HDIM; ++f) acc[f] = b[f];  // uniform -> s_load
#pragma unroll
    for (int k4 = 0; k4 < K / 4; ++k4) {
#pragma unroll
      for (int j = 0; j < 4; ++j) {
        float xs = elem4(row[k4], j);
        int k = k4 * 4 + j;
#pragma unroll
        for (int f = 0; f < HDIM; ++f) acc[f] += xs * W[k * HDIM + f];
      }
    }
  }
  store_rows_bf16(xbout + (size_t)base * HDIM, st, acc, node0, rows, tid, active);
}

// ---------------- coarse histogram: LDS-aggregated, 293 bins ----------------
__global__ __launch_bounds__(256) void coarse_hist_kernel(const int* __restrict__ dst,
                                                          int* __restrict__ chist, int e) {
  __shared__ int h[NCB];
  int tid = threadIdx.x;
  int start = blockIdx.x * CHUNK;
  int len = min(CHUNK, e - start);
  for (int i = tid; i < NCB; i += 256) h[i] = 0;
  __syncthreads();
  for (int i = tid; i < len; i += 256) atomicAdd(&h[dst[start + i] >> 10], 1);
  __syncthreads();
  for (int b = tid; b < NCB; b += 256) {
    int c = h[b];
    if (c > 0) atomicAdd(&chist[b], c);
  }
}

// ---------------- exclusive scan of 293 coarse counts ----------------
__global__ __launch_bounds__(512) void coarse_scan_kernel(const int* __restrict__ chist,
                                                          int* __restrict__ cbase,
                                                          int* __restrict__ ccur) {
  __shared__ int sv[512];
  int t = threadIdx.x;
  sv[t] = (t < NCB) ? chist[t] : 0;
  __syncthreads();
  for (int o = 1; o < 512; o <<= 1) {
    int y = (t >= o) ? sv[t - o] : 0;
    __syncthreads();
    sv[t] += y;
    __syncthreads();
  }
  if (t < NCB) {
    int ex = (t == 0) ? 0 : sv[t - 1];
    cbase[t] = ex;
    ccur[t] = ex;
  }
}

// ---------------- coarse scatter: block-aggregated reservation, dense runs ----------------
// packed word = (src << 10) | (dst & 1023); src < 2^19 -> 29 bits.
__global__ __launch_bounds__(256) void coarse_scatter_kernel(
    const int* __restrict__ src, const int* __restrict__ dst,
    int* __restrict__ ccur, unsigned* __restrict__ packed, int e) {
  __shared__ int h[NCB];
  __shared__ int lbase[NCB];
  int tid = threadIdx.x;
  int start = blockIdx.x * CHUNK;
  int len = min(CHUNK, e - start);
  for (int i = tid; i < NCB; i += 256) h[i] = 0;
  __syncthreads();
  for (int i = tid; i < len; i += 256) atomicAdd(&h[dst[start + i] >> 10], 1);
  __syncthreads();
  for (int b = tid; b < NCB; b += 256) {
    int c = h[b];
    lbase[b] = (c > 0) ? atomicAdd(&ccur[b], c) : 0;  // reserve contiguous run
  }
  __syncthreads();
  for (int i = tid; i < NCB; i += 256) h[i] = 0;  // reuse as rank counters
  __syncthreads();
  for (int i = tid; i < len; i += 256) {
    int d = dst[start + i];
    int s = src[start + i];
    int b = d >> 10;
    int r = atomicAdd(&h[b], 1);
    packed[lbase[b] + r] = ((unsigned)s << 10) | (unsigned)(d & 1023);
  }
}

// ---------------- per-coarse-bucket counting sort -> node-grouped CSR ----------------
__global__ __launch_bounds__(256) void sort_coarse_kernel(
    const unsigned* __restrict__ packed, const int* __restrict__ cbase,
    const int* __restrict__ chist, int* __restrict__ eidx,
    int* __restrict__ nodeoff, int* __restrict__ deg) {
  __shared__ int cnts[1024];
  __shared__ int cur[1024];
  __shared__ int part[256];
  int cb = blockIdx.x;
  int tid = threadIdx.x;
  for (int i = tid; i < 1024; i += 256) cnts[i] = 0;
  __syncthreads();
  int base = cbase[cb];
  int cnt = chist[cb];
  for (int i = tid; i < cnt; i += 256)
    atomicAdd(&cnts[packed[base + i] & 1023u], 1);
  __syncthreads();
  int c0 = cnts[4 * tid + 0], c1 = cnts[4 * tid + 1];
  int c2 = cnts[4 * tid + 2], c3 = cnts[4 * tid + 3];
  part[tid] = c0 + c1 + c2 + c3;
  __syncthreads();
  for (int o = 1; o < 256; o <<= 1) {
    int y = (tid >= o) ? part[tid - o] : 0;
    __syncthreads();
    part[tid] += y;
    __syncthreads();
  }
  int pre = (tid == 0) ? 0 : part[tid - 1];
  int e0 = pre, e1 = e0 + c0, e2 = e1 + c1, e3 = e2 + c2;
  cur[4 * tid + 0] = e0; cur[4 * tid + 1] = e1;
  cur[4 * tid + 2] = e2; cur[4 * tid + 3] = e3;
  int nodebase = (cb << 10) + 4 * tid;
  if (nodebase + 0 < NTOT) { deg[nodebase + 0] = c0; nodeoff[nodebase + 0] = base + e0; }
  if (nodebase + 1 < NTOT) { deg[nodebase + 1] = c1; nodeoff[nodebase + 1] = base + e1; }
  if (nodebase + 2 < NTOT) { deg[nodebase + 2] = c2; nodeoff[nodebase + 2] = base + e2; }
  if (nodebase + 3 < NTOT) { deg[nodebase + 3] = c3; nodeoff[nodebase + 3] = base + e3; }
  __syncthreads();
  for (int i = tid; i < cnt; i += 256) {
    unsigned pr = packed[base + i];
    int dl = (int)(pr & 1023u);
    int r = atomicAdd(&cur[dl], 1);
    eidx[base + r] = (int)(pr >> 10);  // 64 KB region exclusive to this block
  }
}

// ---------------- mean aggregation: bf16 in, bf16 out, 16 lanes/node ----------------
__global__ __launch_bounds__(256) void aggregate_kernel(
    const unsigned short* __restrict__ xb, const int* __restrict__ off,
    const int* __restrict__ deg, const int* __restrict__ eidx,
    unsigned short* __restrict__ meanb, int n) {
  int tid = blockIdx.x * 256 + threadIdx.x;
  int node = tid >> 4;
  int lane = tid & 15;
  if (node >= n) return;
  int start = off[node];
  int d = deg[node];
  const v4u* xv = (const v4u*)xb;   // row = 16 x v4u (128 B)
  float4 a0 = make_float4(0.f, 0.f, 0.f, 0.f);
  float4 a1 = make_float4(0.f, 0.f, 0.f, 0.f);
  float4 a2 = make_float4(0.f, 0.f, 0.f, 0.f);
  float4 a3 = make_float4(0.f, 0.f, 0.f, 0.f);
  int i = 0;
  for (; i + 4 <= d; i += 4) {
    int s0 = eidx[start + i + 0];
    int s1 = eidx[start + i + 1];
    int s2 = eidx[start + i + 2];
    int s3 = eidx[start + i + 3];
    v4u v0 = xv[(size_t)s0 * 16 + lane];
    v4u v1 = xv[(size_t)s1 * 16 + lane];
    v4u v2 = xv[(size_t)s2 * 16 + lane];
    v4u v3 = xv[(size_t)s3 * 16 + lane];
    a0.x += bf2f(v0.x); a0.y += bf2f(v0.y); a0.z += bf2f(v0.z); a0.w += bf2f(v0.w);
    a1.x += bf2f(v1.x); a1.y += bf2f(v1.y); a1.z += bf2f(v1.z); a1.w += bf2f(v1.w);
    a2.x += bf2f(v2.x); a2.y += bf2f(v2.y); a2.z += bf2f(v2.z); a2.w += bf2f(v2.w);
    a3.x += bf2f(v3.x); a3.y += bf2f(v3.y); a3.z += bf2f(v3.z); a3.w += bf2f(v3.w);
  }
  for (; i < d; ++i) {
    int s = eidx[start + i];
    v4u v = xv[(size_t)s * 16 + lane];
    a0.x += bf2f(v.x); a0.y += bf2f(v.y); a0.z += bf2f(v.z); a0.w += bf2f(v.w);
  }
  float inv = 1.0f / (float)(d > 0 ? d : 1);
  v4u o;
  o.x = f2bf((a0.x + a1.x + a2.x + a3.x) * inv);
  o.y = f2bf((a0.y + a1.y + a2.y + a3.y) * inv);
  o.z = f2bf((a0.z + a1.z + a2.z + a3.z) * inv);
  o.w = f2bf((a0.w + a1.w + a2.w + a3.w) * inv);
  // mean is a pure stream (read once by combine): keep it out of L3
  __builtin_nontemporal_store(o, (v4u*)meanb + (size_t)node * 16 + lane);
}

// ---------------- combine: relu(mean@Wl + x@Wr + b); out fp32 OR bf16 ----------------
__global__ __launch_bounds__(256, 4) void combine_kernel(
    const unsigned short* __restrict__ meanb, const unsigned short* __restrict__ xb,
    const float* __restrict__ Wl, const float* __restrict__ Wr,
    const float* __restrict__ bb, float* __restrict__ outf,
    unsigned short* __restrict__ outb, int n) {
  __shared__ float st[256 * PADW];
  int tid = threadIdx.x;
  int node0 = blockIdx.x * 256;
  int node = node0 + tid;
  bool active = node < n;
  int rows = min(256, n - node0);
  float acc[HDIM];
  if (active) {
#pragma unroll
    for (int f = 0; f < HDIM; ++f) acc[f] = bb[f];
    // phase 1: mean(bf16) @ Wl  (burst nt-load full row — stream)
    const v4u* mv = (const v4u*)(meanb + (size_t)node * HDIM);
    v4u hrow[16];
#pragma unroll
    for (int i = 0; i < 16; ++i) hrow[i] = __builtin_nontemporal_load(mv + i);
#pragma unroll
    for (int k4 = 0; k4 < 16; ++k4) {
      float ms4[4] = {bf2f(hrow[k4].x), bf2f(hrow[k4].y), bf2f(hrow[k4].z), bf2f(hrow[k4].w)};
#pragma unroll
      for (int j = 0; j < 4; ++j) {
        int k = k4 * 4 + j;
#pragma unroll
        for (int f = 0; f < HDIM; ++f) acc[f] += ms4[j] * Wl[k * HDIM + f];
      }
    }
    // phase 2: x(bf16) @ Wr
    const v4u* xv = (const v4u*)(xb + (size_t)node * HDIM);
#pragma unroll
    for (int i = 0; i < 16; ++i) hrow[i] = xv[i];
#pragma unroll
    for (int k4 = 0; k4 < 16; ++k4) {
      float xs4[4] = {bf2f(hrow[k4].x), bf2f(hrow[k4].y), bf2f(hrow[k4].z), bf2f(hrow[k4].w)};
#pragma unroll
      for (int j = 0; j < 4; ++j) {
        int k = k4 * 4 + j;
#pragma unroll
        for (int f = 0; f < HDIM; ++f) acc[f] += xs4[j] * Wr[k * HDIM + f];
      }
    }
#pragma unroll
    for (int f = 0; f < HDIM; ++f) acc[f] = fmaxf(acc[f], 0.f);
  }
  if (outb) store_rows_bf16(outb, st, acc, node0, rows, tid, active);
  else      store_rows_f32(outf, st, acc, node0, rows, tid, active);
}

// ---------------- classifier: out = relu(x@Wc1+bc1)@Wc2 + bc2  (fp32 input) ----------------
__global__ __launch_bounds__(256, 2) void classifier_kernel(
    const float* __restrict__ x, const float* __restrict__ W1, const float* __restrict__ b1,
    const float* __restrict__ W2, const float* __restrict__ b2,
    float* __restrict__ out, int n) {
  int node = blockIdx.x * 256 + threadIdx.x;
  if (node >= n) return;
  float4 row[16];
  const float4* xv = (const float4*)(x + (size_t)node * HDIM);
#pragma unroll
  for (int i = 0; i < 16; ++i) row[i] = xv[i];
  float h[32];
#pragma unroll
  for (int f = 0; f < 32; ++f) h[f] = b1[f];
#pragma unroll
  for (int k4 = 0; k4 < 16; ++k4) {
#pragma unroll
    for (int j = 0; j < 4; ++j) {
      float xs = elem4(row[k4], j);
      int k = k4 * 4 + j;
#pragma unroll
      for (int f = 0; f < 32; ++f) h[f] += xs * W1[k * 32 + f];
    }
  }
  float o0 = b2[0], o1 = b2[1];
#pragma unroll
  for (int f = 0; f < 32; ++f) {
    float hv = fmaxf(h[f], 0.f);
    o0 += hv * W2[f * 2 + 0];
    o1 += hv * W2[f * 2 + 1];
  }
  float2 o;
  o.x = o0; o.y = o1;
  *(float2*)(out + (size_t)node * 2) = o;   // lane-consecutive: already coalesced
}

extern "C" void kernel_launch(void* const* d_in, const int* in_sizes, int n_in,
                              void* d_out, int out_size, void* d_ws, size_t ws_size,
                              hipStream_t stream) {
  const float* x_ind = (const float*)d_in[0];
  const float* x_com = (const float*)d_in[1];
  const float* x_tru = (const float*)d_in[2];
  const int*   ei    = (const int*)d_in[3];
  const float* W_ind = (const float*)d_in[4];
  const float* b_ind = (const float*)d_in[5];
  const float* W_com = (const float*)d_in[6];
  const float* b_com = (const float*)d_in[7];
  const float* W_tru = (const float*)d_in[8];
  const float* b_tru = (const float*)d_in[9];
  const float* W1l = (const float*)d_in[10];
  const float* W1r = (const float*)d_in[11];
  const float* b1  = (const float*)d_in[12];
  const float* W2l = (const float*)d_in[13];
  const float* W2r = (const float*)d_in[14];
  const float* b2  = (const float*)d_in[15];
  const float* Wc1 = (const float*)d_in[16];
  const float* bc1 = (const float*)d_in[17];
  const float* Wc2 = (const float*)d_in[18];
  const float* bc2 = (const float*)d_in[19];

  const int* srcp = ei;           // edge_index[0]
  const int* dstp = ei + NEDGE;   // edge_index[1]

  // workspace layout (~212 MB; round-1 proved >=252 MB available)
  size_t fcount = (size_t)NTOT * HDIM;  // 19.2M elems per feature tensor
  float* xf = (float*)d_ws;                        // fp32 final features (76.8 MB)
  unsigned* packed = (unsigned*)xf;                // ALIAS: dead before xf written
  unsigned short* xb0 = (unsigned short*)(xf + fcount);   // bf16 layer-0 features
  unsigned short* xb1 = xb0 + fcount;                     // bf16 layer-1 features
  unsigned short* mnb = xb1 + fcount;                     // bf16 mean (stream)
  int* eidx    = (int*)(mnb + fcount);
  int* nodeoff = eidx + NEDGE;
  int* deg     = nodeoff + NTOT;
  int* chist   = deg + NTOT;
  int* cbase   = chist + NCB;
  int* ccur    = cbase + NCB;
  size_t needed = (size_t)((char*)(ccur + NCB) - (char*)d_ws) + 64;
  if (ws_size < needed) return;  // would corrupt; fail visibly instead

  (void)hipMemsetAsync(chist, 0, (size_t)NCB * sizeof(int), stream);

  // encoders (write bf16 xb0; independent of edge pipeline)
  encode_kernel<32><<<(N_IND + 255) / 256, 256, 0, stream>>>(x_ind, W_ind, b_ind, xb0, N_IND, 0);
  encode_kernel<48><<<(N_COM + 255) / 256, 256, 0, stream>>>(x_com, W_com, b_com, xb0, N_COM, N_IND);
  encode_kernel<24><<<(N_TRU + 255) / 256, 256, 0, stream>>>(x_tru, W_tru, b_tru, xb0, N_TRU, N_IND + N_COM);

  // coarse partition -> per-coarse-bucket counting sort -> node-grouped CSR
  coarse_hist_kernel<<<NCHUNKS, 256, 0, stream>>>(dstp, chist, NEDGE);
  coarse_scan_kernel<<<1, 512, 0, stream>>>(chist, cbase, ccur);
  coarse_scatter_kernel<<<NCHUNKS, 256, 0, stream>>>(srcp, dstp, ccur, packed, NEDGE);
  sort_coarse_kernel<<<NCB, 256, 0, stream>>>(packed, cbase, chist, eidx, nodeoff, deg);

  // SAGE layer 1: aggregate bf16 -> bf16 mean; combine -> bf16 x1
  aggregate_kernel<<<(NTOT * 16 + 255) / 256, 256, 0, stream>>>(xb0, nodeoff, deg, eidx, mnb, NTOT);
  combine_kernel<<<(NTOT + 255) / 256, 256, 0, stream>>>(mnb, xb0, W1l, W1r, b1, nullptr, xb1, NTOT);

  // SAGE layer 2: aggregate bf16 -> bf16 mean; combine -> fp32 xf
  aggregate_kernel<<<(NTOT * 16 + 255) / 256, 256, 0, stream>>>(xb1, nodeoff, deg, eidx, mnb, NTOT);
  combine_kernel<<<(NTOT + 255) / 256, 256, 0, stream>>>(mnb, xb1, W2l, W2r, b2, xf, nullptr, NTOT);

  // classifier (fp32 input, unquantized)
  classifier_kernel<<<(NTOT + 255) / 256, 256, 0, stream>>>(xf, Wc1, bc1, Wc2, bc2,
                                                            (float*)d_out, NTOT);
}